// Round 9
// baseline (140.479 us; speedup 1.0000x reference)
//
#include <hip/hip_runtime.h>
#include <hip/hip_bf16.h>

#define V_ 3
#define B_ 2
#define C_ 256
#define N_ 1024
#define L_ 3072
#define NH 4
#define DH 64
#define SCALE 0.125f
#define LOG2E 1.44269504088896340736f

typedef __attribute__((ext_vector_type(8))) short short8;
typedef __attribute__((ext_vector_type(4))) float floatx4;
typedef unsigned short u16;
typedef unsigned int u32;

__device__ __forceinline__ u16 f2bf(float f) {
    union { float f; u32 u; } c; c.f = f;
    u32 u = c.u;
    u32 lsb = (u >> 16) & 1u;
    u += 0x7fffu + lsb;
    return (u16)(u >> 16);
}
__device__ __forceinline__ u32 pk_bf16(float a, float b) {
    __hip_bfloat162 h = __float22bfloat162_rn(make_float2(a, b));
    union { __hip_bfloat162 h; u32 u; } cv; cv.h = h; return cv.u;
}

// ---------------------------------------------------------------------------
// K0: fused  (a) features fp32 [V,B,C,N] -> x bf16 [B,L,C]   (384 blocks)
//            (b) weights fp32 -> bf16 Wb[4][65536]           (64 blocks)
// ---------------------------------------------------------------------------
__global__ __launch_bounds__(256) void k_prep_gather(
    const float* __restrict__ feat,
    const float* __restrict__ Wq, const float* __restrict__ Wk,
    const float* __restrict__ Wv, const float* __restrict__ Wp,
    u16* __restrict__ x, u16* __restrict__ Wb) {
    int bid = blockIdx.x;
    int t = threadIdx.x;
    if (bid < 384) {
        __shared__ u16 tile[64][66];
        int n0 = (bid & 15) << 6;
        int c0 = ((bid >> 4) & 3) << 6;
        int b  = (bid >> 6) & 1;
        int v  = bid >> 7;
        const float* src = feat + ((size_t)((v * B_ + b) * C_ + c0)) * N_ + n0;
        for (int i = 0; i < 8; ++i) {
            int idx = i * 256 + t;
            int cl = idx >> 5;
            int np2 = idx & 31;
            float2 f = *(const float2*)(src + (size_t)cl * N_ + np2 * 2);
            *(u32*)&tile[cl][np2 * 2] = pk_bf16(f.x, f.y);
        }
        __syncthreads();
        u16* dst = x + ((size_t)(b * L_ + v * N_ + n0)) * C_ + c0;
        for (int i = 0; i < 8; ++i) {
            int idx = i * 256 + t;
            int nl = idx >> 5;
            int cl = (idx & 31) * 2;
            u32 uu = (u32)tile[cl][nl] | ((u32)tile[cl + 1][nl] << 16);
            *(u32*)(dst + (size_t)nl * C_ + cl) = uu;
        }
    } else {
        int idx = (bid - 384) * 256 + t;
        int g0 = idx * 16;
        int m = g0 >> 16;
        const float* src = (m == 0) ? Wq : (m == 1) ? Wk : (m == 2) ? Wv : Wp;
        int off = g0 & 65535;
#pragma unroll
        for (int e = 0; e < 8; ++e) {
            float2 f = *(const float2*)(src + off + e * 2);
            ((u32*)(Wb + g0))[e] = pk_bf16(f.x, f.y);
        }
    }
}

// ---------------------------------------------------------------------------
// K1: QKV.  grid 2304 = 3 matrices x B x (L/32) x 4 np-chunks, 1 wave.
// Q/K: swapped-operand mfma(W, x) => lane's 4 outputs contiguous => b64 stores.
// V: original orientation (stores already 2xb32).
// Q pre-scaled by SCALE*LOG2E.
// ---------------------------------------------------------------------------
__global__ __launch_bounds__(64) void k_qkv(
    const u16* __restrict__ x, const u16* __restrict__ Wb,
    const float* __restrict__ bq, const float* __restrict__ bk,
    const float* __restrict__ bv,
    u16* __restrict__ Qf, u16* __restrict__ Kf, u16* __restrict__ Vf) {
    int bid = blockIdx.x;
    int npc = bid & 3;
    int rest = bid >> 2;
    int m  = rest / 192;         // 0=q 1=k 2=v
    int rb = rest % 192;
    int b  = rb / 96;
    int r0 = (rb % 96) * 32;
    int lane = threadIdx.x;
    int quad = lane >> 4, m16 = lane & 15;

    const u16* xrow0 = x + ((size_t)(b * L_ + r0 + m16)) * C_ + quad * 8;
    const u16* xrow1 = xrow0 + (size_t)16 * C_;
    short8 a0[8], a1[8];
#pragma unroll
    for (int kc = 0; kc < 8; ++kc) {
        a0[kc] = *(const short8*)(xrow0 + kc * 32);
        a1[kc] = *(const short8*)(xrow1 + kc * 32);
    }
    const u16* W = Wb + (size_t)m * 65536;

    if (m == 2) {
        // ---- V path (original orientation) ----
#pragma unroll
        for (int np = npc * 2; np < npc * 2 + 2; ++np) {
            int nt0 = np * 2;
            const u16* w0 = W + (size_t)(nt0 * 16 + m16) * C_ + quad * 8;
            const u16* w1 = w0 + 16 * C_;
            short8 wf0[8], wf1[8];
#pragma unroll
            for (int kc = 0; kc < 8; ++kc) {
                wf0[kc] = *(const short8*)(w0 + kc * 32);
                wf1[kc] = *(const short8*)(w1 + kc * 32);
            }
            floatx4 acc00 = {0.f,0.f,0.f,0.f}, acc01 = {0.f,0.f,0.f,0.f};
            floatx4 acc10 = {0.f,0.f,0.f,0.f}, acc11 = {0.f,0.f,0.f,0.f};
#pragma unroll
            for (int kc = 0; kc < 8; ++kc) {
                acc00 = __builtin_amdgcn_mfma_f32_16x16x32_bf16(a0[kc], wf0[kc], acc00, 0, 0, 0);
                acc01 = __builtin_amdgcn_mfma_f32_16x16x32_bf16(a0[kc], wf1[kc], acc01, 0, 0, 0);
                acc10 = __builtin_amdgcn_mfma_f32_16x16x32_bf16(a1[kc], wf0[kc], acc10, 0, 0, 0);
                acc11 = __builtin_amdgcn_mfma_f32_16x16x32_bf16(a1[kc], wf1[kc], acc11, 0, 0, 0);
            }
#pragma unroll
            for (int gi = 0; gi < 2; ++gi)
#pragma unroll
            for (int half = 0; half < 2; ++half) {
                int dout = (nt0 + half) * 16 + m16;
                float bias = bv[dout];
                int h = dout >> 6, dh = dout & 63;
                size_t bh = (size_t)(b * NH + h);
                floatx4 acc = gi ? (half ? acc11 : acc10) : (half ? acc01 : acc00);
                float f0 = acc[0] + bias, f1 = acc[1] + bias;
                float f2 = acc[2] + bias, f3 = acc[3] + bias;
                int lr0 = r0 + gi * 16 + quad * 4;
                int tile = lr0 >> 6, kk = lr0 & 63;
                int halfv = kk >> 5, quadp = (kk >> 3) & 3, j0 = kk & 7;
                int ntv = dh >> 4, m16pp = dh & 15;
                u32* p = (u32*)(Vf + (bh * 48 + tile) * 4096 +
                                ((size_t)((ntv * 2 + halfv) * 64 + quadp * 16 + m16pp)) * 8 + j0);
                p[0] = pk_bf16(f0, f1);
                p[1] = pk_bf16(f2, f3);
            }
        }
    } else {
        // ---- Q/K path (swapped operands: D rows = channels) ----
        const float* bs = (m == 0) ? bq : bk;
        float scale = (m == 0) ? (SCALE * LOG2E) : 1.0f;
#pragma unroll
        for (int np = npc * 2; np < npc * 2 + 2; ++np) {
            int nt0 = np * 2;
            const u16* w0 = W + (size_t)(nt0 * 16 + m16) * C_ + quad * 8;
            const u16* w1 = w0 + 16 * C_;
            short8 wf0[8], wf1[8];
#pragma unroll
            for (int kc = 0; kc < 8; ++kc) {
                wf0[kc] = *(const short8*)(w0 + kc * 32);
                wf1[kc] = *(const short8*)(w1 + kc * 32);
            }
            floatx4 acc00 = {0.f,0.f,0.f,0.f}, acc01 = {0.f,0.f,0.f,0.f};
            floatx4 acc10 = {0.f,0.f,0.f,0.f}, acc11 = {0.f,0.f,0.f,0.f};
#pragma unroll
            for (int kc = 0; kc < 8; ++kc) {
                acc00 = __builtin_amdgcn_mfma_f32_16x16x32_bf16(wf0[kc], a0[kc], acc00, 0, 0, 0);
                acc01 = __builtin_amdgcn_mfma_f32_16x16x32_bf16(wf0[kc], a1[kc], acc01, 0, 0, 0);
                acc10 = __builtin_amdgcn_mfma_f32_16x16x32_bf16(wf1[kc], a0[kc], acc10, 0, 0, 0);
                acc11 = __builtin_amdgcn_mfma_f32_16x16x32_bf16(wf1[kc], a1[kc], acc11, 0, 0, 0);
            }
#pragma unroll
            for (int tt = 0; tt < 2; ++tt)
#pragma unroll
            for (int gi = 0; gi < 2; ++gi) {
                int ntb = (nt0 + tt) * 16;
                int h = ntb >> 6;
                size_t bh = (size_t)(b * NH + h);
                int dh0 = (ntb & 63) + quad * 4;
                int cc = dh0 >> 5, qp = (dh0 >> 3) & 3, j0 = dh0 & 7;
                float4 b4 = *(const float4*)(bs + ntb + quad * 4);
                floatx4 acc = tt ? (gi ? acc11 : acc10) : (gi ? acc01 : acc00);
                float f0 = (acc[0] + b4.x) * scale, f1 = (acc[1] + b4.y) * scale;
                float f2 = (acc[2] + b4.z) * scale, f3 = (acc[3] + b4.w) * scale;
                uint2 pk;
                pk.x = pk_bf16(f0, f1);
                pk.y = pk_bf16(f2, f3);
                int token = r0 + gi * 16 + m16;
                if (m == 0) {
                    int grp = (r0 >> 4) + gi;
                    *(uint2*)(Qf + (bh * 192 + grp) * 1024 +
                              (size_t)(cc * 64 + qp * 16 + m16) * 8 + j0) = pk;
                } else {
                    int tile = token >> 6;
                    int ntk = ((r0 & 63) >> 4) + gi;
                    *(uint2*)(Kf + (bh * 48 + tile) * 4096 +
                              (size_t)((ntk * 2 + cc) * 64 + qp * 16 + m16) * 8 + j0) = pk;
                }
            }
        }
    }
}

// ---------------------------------------------------------------------------
// K2: flash attention, S^T formulation, cross-block split-K (2 chunks) +
// in-block split (4 waves x 6 tiles).  48 q-rows/wave.  Shared kv[8] regs
// between K-phase and V-phase to cut pressure.  Writes fp32 partials.
// grid = 2 x B*NH*(L/48) = 1024 blocks.
// ---------------------------------------------------------------------------
__global__ __launch_bounds__(256, 3) void k_attn(
    const u16* __restrict__ Qf, const u16* __restrict__ Kf,
    const u16* __restrict__ Vf, float* __restrict__ o_p, float* __restrict__ l_p) {
    __shared__ __align__(16) char smem[36864];   // PL (27648B) then o_red
    __shared__ float l_red[3][3][16];
    u16* PL = (u16*)smem;
    float* o_red = (float*)smem;
    int bid = blockIdx.x;
    int rest = bid & 511;
    int s  = bid >> 9;
    int qt = rest & 63;
    int h  = (rest >> 6) & 3;
    int b  = rest >> 8;
    int lane = threadIdx.x & 63;
    int w    = threadIdx.x >> 6;
    int quad = lane >> 4, m16 = lane & 15;
    size_t bh = (size_t)(b * NH + h);

    const u16* qbase = Qf + (bh * 192 + qt * 3) * 1024 + (size_t)lane * 8;
    const u16* kbase = Kf + bh * 48 * 4096 + (size_t)lane * 8;
    const u16* vbase = Vf + bh * 48 * 4096 + (size_t)lane * 8;

    short8 aq[3][2];
#pragma unroll
    for (int g = 0; g < 3; ++g) {
        aq[g][0] = *(const short8*)(qbase + g * 1024);
        aq[g][1] = *(const short8*)(qbase + g * 1024 + 512);
    }

    float l_s[3] = {0.f, 0.f, 0.f};
    floatx4 o_acc[3][4];
#pragma unroll
    for (int g = 0; g < 3; ++g)
#pragma unroll
        for (int nt = 0; nt < 4; ++nt) o_acc[g][nt] = (floatx4){0.f, 0.f, 0.f, 0.f};

    int kt0 = s * 24 + w * 6;
    short8 kv[8];

    for (int i = 0; i < 6; ++i) {
        size_t tbase = (size_t)(kt0 + i) * 4096;
        // K phase
#pragma unroll
        for (int f = 0; f < 8; ++f)
            kv[f] = *(const short8*)(kbase + tbase + f * 512);
#pragma unroll
        for (int g = 0; g < 3; ++g) {
            floatx4 sx[4];
#pragma unroll
            for (int nt = 0; nt < 4; ++nt) {
                floatx4 z = {0.f, 0.f, 0.f, 0.f};
                z = __builtin_amdgcn_mfma_f32_16x16x32_bf16(kv[nt * 2], aq[g][0], z, 0, 0, 0);
                sx[nt] = __builtin_amdgcn_mfma_f32_16x16x32_bf16(kv[nt * 2 + 1], aq[g][1], z, 0, 0, 0);
            }
            u16* plrow = PL + (((w * 3 + g) * 16) + m16) * 72;
            float lsum = 0.f;
#pragma unroll
            for (int nt = 0; nt < 4; ++nt) {
                float p0 = __builtin_amdgcn_exp2f(sx[nt][0]);
                float p1 = __builtin_amdgcn_exp2f(sx[nt][1]);
                float p2 = __builtin_amdgcn_exp2f(sx[nt][2]);
                float p3 = __builtin_amdgcn_exp2f(sx[nt][3]);
                lsum += (p0 + p1) + (p2 + p3);
                uint2 pk; pk.x = pk_bf16(p0, p1); pk.y = pk_bf16(p2, p3);
                *(uint2*)(plrow + nt * 16 + quad * 4) = pk;
            }
            l_s[g] += lsum;
        }
        // V phase (reuse kv regs)
#pragma unroll
        for (int f = 0; f < 8; ++f)
            kv[f] = *(const short8*)(vbase + tbase + f * 512);
#pragma unroll
        for (int g = 0; g < 3; ++g) {
            const u16* plrow = PL + (((w * 3 + g) * 16) + m16) * 72;
            short8 bp0 = *(const short8*)(plrow + quad * 8);
            short8 bp1 = *(const short8*)(plrow + 32 + quad * 8);
#pragma unroll
            for (int nt = 0; nt < 4; ++nt) {
                o_acc[g][nt] = __builtin_amdgcn_mfma_f32_16x16x32_bf16(kv[nt * 2], bp0, o_acc[g][nt], 0, 0, 0);
                o_acc[g][nt] = __builtin_amdgcn_mfma_f32_16x16x32_bf16(kv[nt * 2 + 1], bp1, o_acc[g][nt], 0, 0, 0);
            }
        }
    }
    // per-wave l: sum across quads (same q=m16)
    float l_row[3];
#pragma unroll
    for (int g = 0; g < 3; ++g) {
        float ps = l_s[g];
        ps += __shfl_xor(ps, 16);
        ps += __shfl_xor(ps, 32);
        l_row[g] = ps;
    }
    __syncthreads();
    if (w > 0) {
#pragma unroll
        for (int g = 0; g < 3; ++g) {
#pragma unroll
            for (int nt = 0; nt < 4; ++nt)
                *(floatx4*)&o_red[(((w - 1) * 3 + g) * 4 + nt) * 256 + lane * 4] = o_acc[g][nt];
            if (quad == 0) l_red[w - 1][g][m16] = l_row[g];
        }
    }
    __syncthreads();
    if (w == 0) {
#pragma unroll
        for (int g = 0; g < 3; ++g) {
            if (quad == 0)
                l_p[(size_t)bid * 48 + g * 16 + m16] =
                    l_row[g] + l_red[0][g][m16] + l_red[1][g][m16] + l_red[2][g][m16];
#pragma unroll
            for (int nt = 0; nt < 4; ++nt) {
                floatx4 tot = o_acc[g][nt];
#pragma unroll
                for (int w1 = 0; w1 < 3; ++w1)
                    tot += *(const floatx4*)&o_red[((w1 * 3 + g) * 4 + nt) * 256 + lane * 4];
                *(floatx4*)&o_p[(((size_t)bid * 3 + g) * 4 + nt) * 256 + lane * 4] = tot;
            }
        }
    }
}

// ---------------------------------------------------------------------------
// K2b: combine the 2 key-split partials -> o bf16 [B,L,C].  grid 512 x 192.
// ---------------------------------------------------------------------------
__global__ __launch_bounds__(192) void k_comb(
    const float* __restrict__ o_p, const float* __restrict__ l_p,
    u16* __restrict__ o) {
    int bid = blockIdx.x;
    int qt = bid & 63;
    int h  = (bid >> 6) & 3;
    int b  = bid >> 8;
    int lane = threadIdx.x & 63;
    int g    = threadIdx.x >> 6;
    int quad = lane >> 4, m16 = lane & 15;
    float l = l_p[(size_t)bid * 48 + g * 16 + m16] +
              l_p[(size_t)(bid + 512) * 48 + g * 16 + m16];
    float lt = __builtin_amdgcn_rcpf(l);
#pragma unroll
    for (int nt = 0; nt < 4; ++nt) {
        floatx4 t0 = *(const floatx4*)&o_p[(((size_t)bid * 3 + g) * 4 + nt) * 256 + lane * 4];
        floatx4 t1 = *(const floatx4*)&o_p[(((size_t)(bid + 512) * 3 + g) * 4 + nt) * 256 + lane * 4];
        floatx4 tot = t0 + t1;
        uint2 pk;
        pk.x = pk_bf16(tot[0] * lt, tot[1] * lt);
        pk.y = pk_bf16(tot[2] * lt, tot[3] * lt);
        *(uint2*)(o + ((size_t)(b * L_ + qt * 48 + g * 16 + m16)) * C_ +
                  h * 64 + nt * 16 + quad * 4) = pk;
    }
}

// ---------------------------------------------------------------------------
// K3: per-view proj + LayerNorm, swapped operands (D rows = channels).
// grid = V*B*(N/16) = 384 blocks, 4 waves; b64 stores to oln[v][b][n][c].
// ---------------------------------------------------------------------------
__global__ __launch_bounds__(256) void k_proj_ln(
    const u16* __restrict__ o, const u16* __restrict__ Wpb,
    const float* __restrict__ bp,
    const float* __restrict__ gamma, const float* __restrict__ beta,
    u16* __restrict__ oln) {
    __shared__ float sred[4][16];
    __shared__ float sred2[4][16];
    int bid = blockIdx.x;
    int n0 = (bid & 63) << 4;
    int b  = (bid >> 6) & 1;
    int v  = bid >> 7;
    int lane = threadIdx.x & 63;
    int w    = threadIdx.x >> 6;
    int quad = lane >> 4, m16 = lane & 15;

    const u16* orow = o + ((size_t)(b * L_ + v * N_ + n0 + m16)) * C_ + quad * 8;
    short8 a[8];
#pragma unroll
    for (int kc = 0; kc < 8; ++kc) a[kc] = *(const short8*)(orow + kc * 32);

    float pr[4][4];
#pragma unroll
    for (int j = 0; j < 4; ++j) {
        int nt = w * 4 + j;
        const u16* wrow = Wpb + (size_t)(nt * 16 + m16) * C_ + quad * 8;
        floatx4 acc = {0.f, 0.f, 0.f, 0.f};
#pragma unroll
        for (int kc = 0; kc < 8; ++kc) {
            short8 bfr = *(const short8*)(wrow + kc * 32);
            acc = __builtin_amdgcn_mfma_f32_16x16x32_bf16(bfr, a[kc], acc, 0, 0, 0);
        }
        float4 b4 = *(const float4*)(bp + nt * 16 + quad * 4);
        pr[j][0] = acc[0] + b4.x; pr[j][1] = acc[1] + b4.y;
        pr[j][2] = acc[2] + b4.z; pr[j][3] = acc[3] + b4.w;
    }
    // mean over c for token m16
    float sm = 0.f;
#pragma unroll
    for (int j = 0; j < 4; ++j)
        sm += (pr[j][0] + pr[j][1]) + (pr[j][2] + pr[j][3]);
    sm += __shfl_xor(sm, 16);
    sm += __shfl_xor(sm, 32);
    if (quad == 0) sred[w][m16] = sm;
    __syncthreads();
    float mu = (sred[0][m16] + sred[1][m16] + sred[2][m16] + sred[3][m16]) * (1.0f / C_);
    float sq = 0.f;
#pragma unroll
    for (int j = 0; j < 4; ++j)
#pragma unroll
        for (int r = 0; r < 4; ++r) { float d = pr[j][r] - mu; sq += d * d; }
    sq += __shfl_xor(sq, 16);
    sq += __shfl_xor(sq, 32);
    if (quad == 0) sred2[w][m16] = sq;
    __syncthreads();
    float var = (sred2[0][m16] + sred2[1][m16] + sred2[2][m16] + sred2[3][m16]) * (1.0f / C_);
    float rs = __builtin_amdgcn_rsqf(var + 1e-5f);
#pragma unroll
    for (int j = 0; j < 4; ++j) {
        int c0 = (w * 4 + j) * 16 + quad * 4;
        float4 g4 = *(const float4*)(gamma + c0);
        float4 be4 = *(const float4*)(beta + c0);
        float f0 = (pr[j][0] - mu) * rs * g4.x + be4.x;
        float f1 = (pr[j][1] - mu) * rs * g4.y + be4.y;
        float f2 = (pr[j][2] - mu) * rs * g4.z + be4.z;
        float f3 = (pr[j][3] - mu) * rs * g4.w + be4.w;
        uint2 pk;
        pk.x = pk_bf16(f0, f1);
        pk.y = pk_bf16(f2, f3);
        *(uint2*)(oln + ((size_t)((v * B_ + b) * N_ + n0 + m16)) * C_ + c0) = pk;
    }
}

// ---------------------------------------------------------------------------
// K4: mean over views + transpose: out[b][c][n] = mean_v oln[v][b][n][c].
// ---------------------------------------------------------------------------
__global__ __launch_bounds__(256) void k_mean_t(
    const u16* __restrict__ oln, float* __restrict__ out) {
    __shared__ float tile[64][65];
    int bid = blockIdx.x;
    int n0 = (bid & 15) << 6;
    int c0 = ((bid >> 4) & 3) << 6;
    int b  = bid >> 6;
    int t = threadIdx.x;
    union { u32 u; float f; } cv;
    for (int i = 0; i < 16; ++i) {
        int idx = i * 256 + t;
        int nl = idx >> 6, cl = idx & 63;
        float sm = 0.f;
#pragma unroll
        for (int v = 0; v < 3; ++v) {
            u16 raw = oln[((size_t)((v * B_ + b) * N_ + n0 + nl)) * C_ + c0 + cl];
            cv.u = ((u32)raw) << 16;
            sm += cv.f;
        }
        tile[cl][nl] = sm * (1.0f / 3.0f);
    }
    __syncthreads();
    for (int i = 0; i < 16; ++i) {
        int idx = i * 256 + t;
        int cl = idx >> 6, nl = idx & 63;
        out[((size_t)(b * C_ + c0 + cl)) * N_ + n0 + nl] = tile[cl][nl];
    }
}

extern "C" void kernel_launch(void* const* d_in, const int* in_sizes, int n_in,
                              void* d_out, int out_size, void* d_ws, size_t ws_size,
                              hipStream_t stream) {
    (void)in_sizes; (void)n_in; (void)out_size; (void)ws_size;
    const float* feat  = (const float*)d_in[0];
    const float* Wq    = (const float*)d_in[1];
    const float* bq    = (const float*)d_in[2];
    const float* Wk    = (const float*)d_in[3];
    const float* bk    = (const float*)d_in[4];
    const float* Wv    = (const float*)d_in[5];
    const float* bv    = (const float*)d_in[6];
    const float* Wp    = (const float*)d_in[7];
    const float* bp    = (const float*)d_in[8];
    const float* gamma = (const float*)d_in[9];
    const float* beta  = (const float*)d_in[10];
    float* out = (float*)d_out;

    size_t SZ = (size_t)B_ * L_ * C_;   // 1,572,864 elements
    u16* x   = (u16*)d_ws;
    u16* Qf  = x + SZ;
    u16* Kf  = Qf + SZ;
    u16* Vf  = Kf + SZ;
    u16* o   = Vf + SZ;
    u16* Wb  = o + SZ;                  // [4][65536] bf16 weights
    u16* oln = Wb + 4 * 65536;          // [V][B][N][C] bf16
    float* o_p = (float*)(oln + SZ);    // 1024*3072 f32 partials
    float* l_p = o_p + (size_t)1024 * 3072;

    k_prep_gather<<<dim3(448), dim3(256), 0, stream>>>(feat, Wq, Wk, Wv, Wp, x, Wb);
    k_qkv<<<dim3(2304), dim3(64), 0, stream>>>(x, Wb, bq, bk, bv, Qf, Kf, Vf);
    k_attn<<<dim3(1024), dim3(256), 0, stream>>>(Qf, Kf, Vf, o_p, l_p);
    k_comb<<<dim3(512), dim3(192), 0, stream>>>(o_p, l_p, o);
    k_proj_ln<<<dim3(384), dim3(256), 0, stream>>>(o, Wb + 3 * 65536, bp, gamma, beta, oln);
    k_mean_t<<<dim3(128), dim3(256), 0, stream>>>(oln, out);
}

// Round 10
// 137.285 us; speedup vs baseline: 1.0233x; 1.0233x over previous
//
#include <hip/hip_runtime.h>
#include <hip/hip_bf16.h>

#define V_ 3
#define B_ 2
#define C_ 256
#define N_ 1024
#define L_ 3072
#define NH 4
#define DH 64
#define SCALE 0.125f
#define LOG2E 1.44269504088896340736f

typedef __attribute__((ext_vector_type(8))) short short8;
typedef __attribute__((ext_vector_type(4))) float floatx4;
typedef unsigned short u16;
typedef unsigned int u32;

__device__ __forceinline__ u16 f2bf(float f) {
    union { float f; u32 u; } c; c.f = f;
    u32 u = c.u;
    u32 lsb = (u >> 16) & 1u;
    u += 0x7fffu + lsb;
    return (u16)(u >> 16);
}
__device__ __forceinline__ u32 pk_bf16(float a, float b) {
    __hip_bfloat162 h = __float22bfloat162_rn(make_float2(a, b));
    union { __hip_bfloat162 h; u32 u; } cv; cv.h = h; return cv.u;
}

// ---------------------------------------------------------------------------
// K0: fused  (a) features fp32 [V,B,C,N] -> x bf16 [B,L,C]   (384 blocks)
//            (b) weights fp32 -> bf16 Wb[4][65536]           (64 blocks)
// ---------------------------------------------------------------------------
__global__ __launch_bounds__(256) void k_prep_gather(
    const float* __restrict__ feat,
    const float* __restrict__ Wq, const float* __restrict__ Wk,
    const float* __restrict__ Wv, const float* __restrict__ Wp,
    u16* __restrict__ x, u16* __restrict__ Wb) {
    int bid = blockIdx.x;
    int t = threadIdx.x;
    if (bid < 384) {
        __shared__ u16 tile[64][66];
        int n0 = (bid & 15) << 6;
        int c0 = ((bid >> 4) & 3) << 6;
        int b  = (bid >> 6) & 1;
        int v  = bid >> 7;
        const float* src = feat + ((size_t)((v * B_ + b) * C_ + c0)) * N_ + n0;
        for (int i = 0; i < 8; ++i) {
            int idx = i * 256 + t;
            int cl = idx >> 5;
            int np2 = idx & 31;
            float2 f = *(const float2*)(src + (size_t)cl * N_ + np2 * 2);
            *(u32*)&tile[cl][np2 * 2] = pk_bf16(f.x, f.y);
        }
        __syncthreads();
        u16* dst = x + ((size_t)(b * L_ + v * N_ + n0)) * C_ + c0;
        for (int i = 0; i < 8; ++i) {
            int idx = i * 256 + t;
            int nl = idx >> 5;
            int cl = (idx & 31) * 2;
            u32 uu = (u32)tile[cl][nl] | ((u32)tile[cl + 1][nl] << 16);
            *(u32*)(dst + (size_t)nl * C_ + cl) = uu;
        }
    } else {
        int idx = (bid - 384) * 256 + t;
        int g0 = idx * 16;
        int m = g0 >> 16;
        const float* src = (m == 0) ? Wq : (m == 1) ? Wk : (m == 2) ? Wv : Wp;
        int off = g0 & 65535;
#pragma unroll
        for (int e = 0; e < 8; ++e) {
            float2 f = *(const float2*)(src + off + e * 2);
            ((u32*)(Wb + g0))[e] = pk_bf16(f.x, f.y);
        }
    }
}

// ---------------------------------------------------------------------------
// K1: QKV.  grid 2304 = 3 matrices x B x (L/32) x 4 np-chunks, 1 wave.
// Q/K: swapped-operand mfma(W, x) => lane's 4 outputs contiguous => b64 stores.
// V: original orientation.  Q pre-scaled by SCALE*LOG2E.
// ---------------------------------------------------------------------------
__global__ __launch_bounds__(64) void k_qkv(
    const u16* __restrict__ x, const u16* __restrict__ Wb,
    const float* __restrict__ bq, const float* __restrict__ bk,
    const float* __restrict__ bv,
    u16* __restrict__ Qf, u16* __restrict__ Kf, u16* __restrict__ Vf) {
    int bid = blockIdx.x;
    int npc = bid & 3;
    int rest = bid >> 2;
    int m  = rest / 192;         // 0=q 1=k 2=v
    int rb = rest % 192;
    int b  = rb / 96;
    int r0 = (rb % 96) * 32;
    int lane = threadIdx.x;
    int quad = lane >> 4, m16 = lane & 15;

    const u16* xrow0 = x + ((size_t)(b * L_ + r0 + m16)) * C_ + quad * 8;
    const u16* xrow1 = xrow0 + (size_t)16 * C_;
    short8 a0[8], a1[8];
#pragma unroll
    for (int kc = 0; kc < 8; ++kc) {
        a0[kc] = *(const short8*)(xrow0 + kc * 32);
        a1[kc] = *(const short8*)(xrow1 + kc * 32);
    }
    const u16* W = Wb + (size_t)m * 65536;

    if (m == 2) {
#pragma unroll
        for (int np = npc * 2; np < npc * 2 + 2; ++np) {
            int nt0 = np * 2;
            const u16* w0 = W + (size_t)(nt0 * 16 + m16) * C_ + quad * 8;
            const u16* w1 = w0 + 16 * C_;
            short8 wf0[8], wf1[8];
#pragma unroll
            for (int kc = 0; kc < 8; ++kc) {
                wf0[kc] = *(const short8*)(w0 + kc * 32);
                wf1[kc] = *(const short8*)(w1 + kc * 32);
            }
            floatx4 acc00 = {0.f,0.f,0.f,0.f}, acc01 = {0.f,0.f,0.f,0.f};
            floatx4 acc10 = {0.f,0.f,0.f,0.f}, acc11 = {0.f,0.f,0.f,0.f};
#pragma unroll
            for (int kc = 0; kc < 8; ++kc) {
                acc00 = __builtin_amdgcn_mfma_f32_16x16x32_bf16(a0[kc], wf0[kc], acc00, 0, 0, 0);
                acc01 = __builtin_amdgcn_mfma_f32_16x16x32_bf16(a0[kc], wf1[kc], acc01, 0, 0, 0);
                acc10 = __builtin_amdgcn_mfma_f32_16x16x32_bf16(a1[kc], wf0[kc], acc10, 0, 0, 0);
                acc11 = __builtin_amdgcn_mfma_f32_16x16x32_bf16(a1[kc], wf1[kc], acc11, 0, 0, 0);
            }
#pragma unroll
            for (int gi = 0; gi < 2; ++gi)
#pragma unroll
            for (int half = 0; half < 2; ++half) {
                int dout = (nt0 + half) * 16 + m16;
                float bias = bv[dout];
                int h = dout >> 6, dh = dout & 63;
                size_t bh = (size_t)(b * NH + h);
                floatx4 acc = gi ? (half ? acc11 : acc10) : (half ? acc01 : acc00);
                float f0 = acc[0] + bias, f1 = acc[1] + bias;
                float f2 = acc[2] + bias, f3 = acc[3] + bias;
                int lr0 = r0 + gi * 16 + quad * 4;
                int tile = lr0 >> 6, kk = lr0 & 63;
                int halfv = kk >> 5, quadp = (kk >> 3) & 3, j0 = kk & 7;
                int ntv = dh >> 4, m16pp = dh & 15;
                u32* p = (u32*)(Vf + (bh * 48 + tile) * 4096 +
                                ((size_t)((ntv * 2 + halfv) * 64 + quadp * 16 + m16pp)) * 8 + j0);
                p[0] = pk_bf16(f0, f1);
                p[1] = pk_bf16(f2, f3);
            }
        }
    } else {
        const float* bs = (m == 0) ? bq : bk;
        float scale = (m == 0) ? (SCALE * LOG2E) : 1.0f;
#pragma unroll
        for (int np = npc * 2; np < npc * 2 + 2; ++np) {
            int nt0 = np * 2;
            const u16* w0 = W + (size_t)(nt0 * 16 + m16) * C_ + quad * 8;
            const u16* w1 = w0 + 16 * C_;
            short8 wf0[8], wf1[8];
#pragma unroll
            for (int kc = 0; kc < 8; ++kc) {
                wf0[kc] = *(const short8*)(w0 + kc * 32);
                wf1[kc] = *(const short8*)(w1 + kc * 32);
            }
            floatx4 acc00 = {0.f,0.f,0.f,0.f}, acc01 = {0.f,0.f,0.f,0.f};
            floatx4 acc10 = {0.f,0.f,0.f,0.f}, acc11 = {0.f,0.f,0.f,0.f};
#pragma unroll
            for (int kc = 0; kc < 8; ++kc) {
                acc00 = __builtin_amdgcn_mfma_f32_16x16x32_bf16(wf0[kc], a0[kc], acc00, 0, 0, 0);
                acc01 = __builtin_amdgcn_mfma_f32_16x16x32_bf16(wf0[kc], a1[kc], acc01, 0, 0, 0);
                acc10 = __builtin_amdgcn_mfma_f32_16x16x32_bf16(wf1[kc], a0[kc], acc10, 0, 0, 0);
                acc11 = __builtin_amdgcn_mfma_f32_16x16x32_bf16(wf1[kc], a1[kc], acc11, 0, 0, 0);
            }
#pragma unroll
            for (int tt = 0; tt < 2; ++tt)
#pragma unroll
            for (int gi = 0; gi < 2; ++gi) {
                int ntb = (nt0 + tt) * 16;
                int h = ntb >> 6;
                size_t bh = (size_t)(b * NH + h);
                int dh0 = (ntb & 63) + quad * 4;
                int cc = dh0 >> 5, qp = (dh0 >> 3) & 3, j0 = dh0 & 7;
                float4 b4 = *(const float4*)(bs + ntb + quad * 4);
                floatx4 acc = tt ? (gi ? acc11 : acc10) : (gi ? acc01 : acc00);
                float f0 = (acc[0] + b4.x) * scale, f1 = (acc[1] + b4.y) * scale;
                float f2 = (acc[2] + b4.z) * scale, f3 = (acc[3] + b4.w) * scale;
                uint2 pk;
                pk.x = pk_bf16(f0, f1);
                pk.y = pk_bf16(f2, f3);
                int token = r0 + gi * 16 + m16;
                if (m == 0) {
                    int grp = (r0 >> 4) + gi;
                    *(uint2*)(Qf + (bh * 192 + grp) * 1024 +
                              (size_t)(cc * 64 + qp * 16 + m16) * 8 + j0) = pk;
                } else {
                    int tile = token >> 6;
                    int ntk = ((r0 & 63) >> 4) + gi;
                    *(uint2*)(Kf + (bh * 48 + tile) * 4096 +
                              (size_t)((ntk * 2 + cc) * 64 + qp * 16 + m16) * 8 + j0) = pk;
                }
            }
        }
    }
}

// ---------------------------------------------------------------------------
// K2: flash attention, S^T formulation, single-level split-K (4 waves x 12
// tiles), 48 q-rows/wave.  P LDS round-trip software-pipelined (lag-by-one
// tile, double-buffered PL) so ds-write->ds-read latency hides under the
// next tile's loads/MFMA.  grid = B*NH*(L/48) = 512 blocks.
// ---------------------------------------------------------------------------
__global__ __launch_bounds__(256, 2) void k_attn(
    const u16* __restrict__ Qf, const u16* __restrict__ Kf,
    const u16* __restrict__ Vf, u16* __restrict__ o) {
    // PL double buffer: 2 x 12(w*3+g) x 16 x 72 u16 = 55296B; reused as o_red.
    __shared__ __align__(16) char smem[55296];
    __shared__ float l_red[3][3][16];
    u16* PL = (u16*)smem;
    float* o_red = (float*)smem;
    int bid = blockIdx.x;
    int qt = bid & 63;
    int h  = (bid >> 6) & 3;
    int b  = bid >> 8;
    int lane = threadIdx.x & 63;
    int w    = threadIdx.x >> 6;
    int quad = lane >> 4, m16 = lane & 15;
    int q0 = qt * 48;
    size_t bh = (size_t)(b * NH + h);

    const u16* qbase = Qf + (bh * 192 + qt * 3) * 1024 + (size_t)lane * 8;
    const u16* kbase = Kf + bh * 48 * 4096 + (size_t)lane * 8;
    const u16* vbase = Vf + bh * 48 * 4096 + (size_t)lane * 8;

    short8 aq[3][2];
#pragma unroll
    for (int g = 0; g < 3; ++g) {
        aq[g][0] = *(const short8*)(qbase + g * 1024);
        aq[g][1] = *(const short8*)(qbase + g * 1024 + 512);
    }

    float l_s[3] = {0.f, 0.f, 0.f};
    floatx4 o_acc[3][4];
#pragma unroll
    for (int g = 0; g < 3; ++g)
#pragma unroll
        for (int nt = 0; nt < 4; ++nt) o_acc[g][nt] = (floatx4){0.f, 0.f, 0.f, 0.f};

    int kt0 = w * 12;
    short8 kb[8], vb[8];

    // ---- prologue: tile 0 -> S, exp, P into PL[0] ----
#pragma unroll
    for (int f = 0; f < 8; ++f)
        kb[f] = *(const short8*)(kbase + (size_t)kt0 * 4096 + f * 512);
#pragma unroll
    for (int g = 0; g < 3; ++g) {
        floatx4 sx[4];
#pragma unroll
        for (int nt = 0; nt < 4; ++nt) {
            floatx4 z = {0.f, 0.f, 0.f, 0.f};
            z = __builtin_amdgcn_mfma_f32_16x16x32_bf16(kb[nt * 2], aq[g][0], z, 0, 0, 0);
            sx[nt] = __builtin_amdgcn_mfma_f32_16x16x32_bf16(kb[nt * 2 + 1], aq[g][1], z, 0, 0, 0);
        }
        u16* plrow = PL + ((0 * 12 + w * 3 + g) * 16 + m16) * 72;
        float lsum = 0.f;
#pragma unroll
        for (int nt = 0; nt < 4; ++nt) {
            float p0 = __builtin_amdgcn_exp2f(sx[nt][0]);
            float p1 = __builtin_amdgcn_exp2f(sx[nt][1]);
            float p2 = __builtin_amdgcn_exp2f(sx[nt][2]);
            float p3 = __builtin_amdgcn_exp2f(sx[nt][3]);
            lsum += (p0 + p1) + (p2 + p3);
            uint2 pk; pk.x = pk_bf16(p0, p1); pk.y = pk_bf16(p2, p3);
            *(uint2*)(plrow + nt * 16 + quad * 4) = pk;
        }
        l_s[g] += lsum;
    }

    // ---- main loop: PV of tile i (P from PL[cur]) + S/P of tile i+1 ----
    for (int i = 0; i < 12; ++i) {
        int cur = i & 1, nxt = cur ^ 1;
        size_t tbase = (size_t)(kt0 + i) * 4096;
        // V loads for tile i (first use below at PV)
#pragma unroll
        for (int f = 0; f < 8; ++f)
            vb[f] = *(const short8*)(vbase + tbase + f * 512);
        // early P reads (written >=1 iteration ago -> latency hidden)
        short8 bp[3][2];
#pragma unroll
        for (int g = 0; g < 3; ++g) {
            const u16* plrow = PL + ((cur * 12 + w * 3 + g) * 16 + m16) * 72;
            bp[g][0] = *(const short8*)(plrow + quad * 8);
            bp[g][1] = *(const short8*)(plrow + 32 + quad * 8);
        }
        // K loads for tile i+1
        if (i < 11) {
#pragma unroll
            for (int f = 0; f < 8; ++f)
                kb[f] = *(const short8*)(kbase + tbase + 4096 + f * 512);
        }
        // PV (waits on vb + bp)
#pragma unroll
        for (int g = 0; g < 3; ++g)
#pragma unroll
            for (int nt = 0; nt < 4; ++nt) {
                o_acc[g][nt] = __builtin_amdgcn_mfma_f32_16x16x32_bf16(vb[nt * 2], bp[g][0], o_acc[g][nt], 0, 0, 0);
                o_acc[g][nt] = __builtin_amdgcn_mfma_f32_16x16x32_bf16(vb[nt * 2 + 1], bp[g][1], o_acc[g][nt], 0, 0, 0);
            }
        // S of tile i+1, exp, write PL[nxt]
        if (i < 11) {
#pragma unroll
            for (int g = 0; g < 3; ++g) {
                floatx4 sx[4];
#pragma unroll
                for (int nt = 0; nt < 4; ++nt) {
                    floatx4 z = {0.f, 0.f, 0.f, 0.f};
                    z = __builtin_amdgcn_mfma_f32_16x16x32_bf16(kb[nt * 2], aq[g][0], z, 0, 0, 0);
                    sx[nt] = __builtin_amdgcn_mfma_f32_16x16x32_bf16(kb[nt * 2 + 1], aq[g][1], z, 0, 0, 0);
                }
                u16* plrow = PL + ((nxt * 12 + w * 3 + g) * 16 + m16) * 72;
                float lsum = 0.f;
#pragma unroll
                for (int nt = 0; nt < 4; ++nt) {
                    float p0 = __builtin_amdgcn_exp2f(sx[nt][0]);
                    float p1 = __builtin_amdgcn_exp2f(sx[nt][1]);
                    float p2 = __builtin_amdgcn_exp2f(sx[nt][2]);
                    float p3 = __builtin_amdgcn_exp2f(sx[nt][3]);
                    lsum += (p0 + p1) + (p2 + p3);
                    uint2 pk; pk.x = pk_bf16(p0, p1); pk.y = pk_bf16(p2, p3);
                    *(uint2*)(plrow + nt * 16 + quad * 4) = pk;
                }
                l_s[g] += lsum;
            }
        }
    }
    // per-wave l: sum across quads (same q=m16)
    float l_row[3];
#pragma unroll
    for (int g = 0; g < 3; ++g) {
        float ps = l_s[g];
        ps += __shfl_xor(ps, 16);
        ps += __shfl_xor(ps, 32);
        l_row[g] = ps;
    }
    __syncthreads();   // all waves done with PL before o_red overwrite
    if (w > 0) {
#pragma unroll
        for (int g = 0; g < 3; ++g) {
#pragma unroll
            for (int nt = 0; nt < 4; ++nt)
                *(floatx4*)&o_red[(((w - 1) * 3 + g) * 4 + nt) * 256 + lane * 4] = o_acc[g][nt];
            if (quad == 0) l_red[w - 1][g][m16] = l_row[g];
        }
    }
    __syncthreads();
    if (w == 0) {
#pragma unroll
        for (int g = 0; g < 3; ++g) {
            float lt = __builtin_amdgcn_rcpf(
                l_row[g] + l_red[0][g][m16] + l_red[1][g][m16] + l_red[2][g][m16]);
#pragma unroll
            for (int nt = 0; nt < 4; ++nt) {
                floatx4 tot = o_acc[g][nt];
#pragma unroll
                for (int w1 = 0; w1 < 3; ++w1)
                    tot += *(const floatx4*)&o_red[((w1 * 3 + g) * 4 + nt) * 256 + lane * 4];
                uint2 pk;
                pk.x = pk_bf16(tot[0] * lt, tot[1] * lt);
                pk.y = pk_bf16(tot[2] * lt, tot[3] * lt);
                *(uint2*)(o + ((size_t)(b * L_ + q0 + g * 16 + m16)) * C_ +
                          h * 64 + nt * 16 + quad * 4) = pk;
            }
        }
    }
}

// ---------------------------------------------------------------------------
// K3: per-view proj + LayerNorm, swapped operands (D rows = channels).
// grid = V*B*(N/16) = 384 blocks, 4 waves; b64 stores to oln[v][b][n][c].
// ---------------------------------------------------------------------------
__global__ __launch_bounds__(256) void k_proj_ln(
    const u16* __restrict__ o, const u16* __restrict__ Wpb,
    const float* __restrict__ bp,
    const float* __restrict__ gamma, const float* __restrict__ beta,
    u16* __restrict__ oln) {
    __shared__ float sred[4][16];
    __shared__ float sred2[4][16];
    int bid = blockIdx.x;
    int n0 = (bid & 63) << 4;
    int b  = (bid >> 6) & 1;
    int v  = bid >> 7;
    int lane = threadIdx.x & 63;
    int w    = threadIdx.x >> 6;
    int quad = lane >> 4, m16 = lane & 15;

    const u16* orow = o + ((size_t)(b * L_ + v * N_ + n0 + m16)) * C_ + quad * 8;
    short8 a[8];
#pragma unroll
    for (int kc = 0; kc < 8; ++kc) a[kc] = *(const short8*)(orow + kc * 32);

    float pr[4][4];
#pragma unroll
    for (int j = 0; j < 4; ++j) {
        int nt = w * 4 + j;
        const u16* wrow = Wpb + (size_t)(nt * 16 + m16) * C_ + quad * 8;
        floatx4 acc = {0.f, 0.f, 0.f, 0.f};
#pragma unroll
        for (int kc = 0; kc < 8; ++kc) {
            short8 bfr = *(const short8*)(wrow + kc * 32);
            acc = __builtin_amdgcn_mfma_f32_16x16x32_bf16(bfr, a[kc], acc, 0, 0, 0);
        }
        float4 b4 = *(const float4*)(bp + nt * 16 + quad * 4);
        pr[j][0] = acc[0] + b4.x; pr[j][1] = acc[1] + b4.y;
        pr[j][2] = acc[2] + b4.z; pr[j][3] = acc[3] + b4.w;
    }
    float sm = 0.f;
#pragma unroll
    for (int j = 0; j < 4; ++j)
        sm += (pr[j][0] + pr[j][1]) + (pr[j][2] + pr[j][3]);
    sm += __shfl_xor(sm, 16);
    sm += __shfl_xor(sm, 32);
    if (quad == 0) sred[w][m16] = sm;
    __syncthreads();
    float mu = (sred[0][m16] + sred[1][m16] + sred[2][m16] + sred[3][m16]) * (1.0f / C_);
    float sq = 0.f;
#pragma unroll
    for (int j = 0; j < 4; ++j)
#pragma unroll
        for (int r = 0; r < 4; ++r) { float d = pr[j][r] - mu; sq += d * d; }
    sq += __shfl_xor(sq, 16);
    sq += __shfl_xor(sq, 32);
    if (quad == 0) sred2[w][m16] = sq;
    __syncthreads();
    float var = (sred2[0][m16] + sred2[1][m16] + sred2[2][m16] + sred2[3][m16]) * (1.0f / C_);
    float rs = __builtin_amdgcn_rsqf(var + 1e-5f);
#pragma unroll
    for (int j = 0; j < 4; ++j) {
        int c0 = (w * 4 + j) * 16 + quad * 4;
        float4 g4 = *(const float4*)(gamma + c0);
        float4 be4 = *(const float4*)(beta + c0);
        float f0 = (pr[j][0] - mu) * rs * g4.x + be4.x;
        float f1 = (pr[j][1] - mu) * rs * g4.y + be4.y;
        float f2 = (pr[j][2] - mu) * rs * g4.z + be4.z;
        float f3 = (pr[j][3] - mu) * rs * g4.w + be4.w;
        uint2 pk;
        pk.x = pk_bf16(f0, f1);
        pk.y = pk_bf16(f2, f3);
        *(uint2*)(oln + ((size_t)((v * B_ + b) * N_ + n0 + m16)) * C_ + c0) = pk;
    }
}

// ---------------------------------------------------------------------------
// K4: mean over views + transpose: out[b][c][n] = mean_v oln[v][b][n][c].
// ---------------------------------------------------------------------------
__global__ __launch_bounds__(256) void k_mean_t(
    const u16* __restrict__ oln, float* __restrict__ out) {
    __shared__ float tile[64][65];
    int bid = blockIdx.x;
    int n0 = (bid & 15) << 6;
    int c0 = ((bid >> 4) & 3) << 6;
    int b  = bid >> 6;
    int t = threadIdx.x;
    union { u32 u; float f; } cv;
    for (int i = 0; i < 16; ++i) {
        int idx = i * 256 + t;
        int nl = idx >> 6, cl = idx & 63;
        float sm = 0.f;
#pragma unroll
        for (int v = 0; v < 3; ++v) {
            u16 raw = oln[((size_t)((v * B_ + b) * N_ + n0 + nl)) * C_ + c0 + cl];
            cv.u = ((u32)raw) << 16;
            sm += cv.f;
        }
        tile[cl][nl] = sm * (1.0f / 3.0f);
    }
    __syncthreads();
    for (int i = 0; i < 16; ++i) {
        int idx = i * 256 + t;
        int cl = idx >> 6, nl = idx & 63;
        out[((size_t)(b * C_ + c0 + cl)) * N_ + n0 + nl] = tile[cl][nl];
    }
}

extern "C" void kernel_launch(void* const* d_in, const int* in_sizes, int n_in,
                              void* d_out, int out_size, void* d_ws, size_t ws_size,
                              hipStream_t stream) {
    (void)in_sizes; (void)n_in; (void)out_size; (void)ws_size;
    const float* feat  = (const float*)d_in[0];
    const float* Wq    = (const float*)d_in[1];
    const float* bq    = (const float*)d_in[2];
    const float* Wk    = (const float*)d_in[3];
    const float* bk    = (const float*)d_in[4];
    const float* Wv    = (const float*)d_in[5];
    const float* bv    = (const float*)d_in[6];
    const float* Wp    = (const float*)d_in[7];
    const float* bp    = (const float*)d_in[8];
    const float* gamma = (const float*)d_in[9];
    const float* beta  = (const float*)d_in[10];
    float* out = (float*)d_out;

    size_t SZ = (size_t)B_ * L_ * C_;   // 1,572,864 elements
    u16* x   = (u16*)d_ws;
    u16* Qf  = x + SZ;
    u16* Kf  = Qf + SZ;
    u16* Vf  = Kf + SZ;
    u16* o   = Vf + SZ;
    u16* Wb  = o + SZ;                  // [4][65536] bf16 weights
    u16* oln = Wb + 4 * 65536;          // [V][B][N][C] bf16

    k_prep_gather<<<dim3(448), dim3(256), 0, stream>>>(feat, Wq, Wk, Wv, Wp, x, Wb);
    k_qkv<<<dim3(2304), dim3(64), 0, stream>>>(x, Wb, bq, bk, bv, Qf, Kf, Vf);
    k_attn<<<dim3(512), dim3(256), 0, stream>>>(Qf, Kf, Vf, o);
    k_proj_ln<<<dim3(384), dim3(256), 0, stream>>>(o, Wb + 3 * 65536, bp, gamma, beta, oln);
    k_mean_t<<<dim3(128), dim3(256), 0, stream>>>(oln, out);
}

// Round 11
// 132.840 us; speedup vs baseline: 1.0575x; 1.0335x over previous
//
#include <hip/hip_runtime.h>
#include <hip/hip_bf16.h>

#define V_ 3
#define B_ 2
#define C_ 256
#define N_ 1024
#define L_ 3072
#define NH 4
#define DH 64
#define SCALE 0.125f
#define LOG2E 1.44269504088896340736f

typedef __attribute__((ext_vector_type(8))) short short8;
typedef __attribute__((ext_vector_type(4))) float floatx4;
typedef unsigned short u16;
typedef unsigned int u32;

__device__ __forceinline__ u32 pk_bf16(float a, float b) {
    __hip_bfloat162 h = __float22bfloat162_rn(make_float2(a, b));
    union { __hip_bfloat162 h; u32 u; } cv; cv.h = h; return cv.u;
}

// ---------------------------------------------------------------------------
// K0: fused  (a) features fp32 [V,B,C,N] -> x bf16 [B,L,C]   (384 blocks)
//            (b) weights fp32 -> bf16 Wb[4][65536]           (64 blocks)
//            (c) zero d_out (atomic accumulation target)     (128 blocks)
// ---------------------------------------------------------------------------
__global__ __launch_bounds__(256) void k_prep_gather(
    const float* __restrict__ feat,
    const float* __restrict__ Wq, const float* __restrict__ Wk,
    const float* __restrict__ Wv, const float* __restrict__ Wp,
    u16* __restrict__ x, u16* __restrict__ Wb, float* __restrict__ out) {
    int bid = blockIdx.x;
    int t = threadIdx.x;
    if (bid < 384) {
        __shared__ u16 tile[64][66];
        int n0 = (bid & 15) << 6;
        int c0 = ((bid >> 4) & 3) << 6;
        int b  = (bid >> 6) & 1;
        int v  = bid >> 7;
        const float* src = feat + ((size_t)((v * B_ + b) * C_ + c0)) * N_ + n0;
        for (int i = 0; i < 8; ++i) {
            int idx = i * 256 + t;
            int cl = idx >> 5;
            int np2 = idx & 31;
            float2 f = *(const float2*)(src + (size_t)cl * N_ + np2 * 2);
            *(u32*)&tile[cl][np2 * 2] = pk_bf16(f.x, f.y);
        }
        __syncthreads();
        u16* dst = x + ((size_t)(b * L_ + v * N_ + n0)) * C_ + c0;
        for (int i = 0; i < 8; ++i) {
            int idx = i * 256 + t;
            int nl = idx >> 5;
            int cl = (idx & 31) * 2;
            u32 uu = (u32)tile[cl][nl] | ((u32)tile[cl + 1][nl] << 16);
            *(u32*)(dst + (size_t)nl * C_ + cl) = uu;
        }
    } else if (bid < 448) {
        int idx = (bid - 384) * 256 + t;
        int g0 = idx * 16;
        int m = g0 >> 16;
        const float* src = (m == 0) ? Wq : (m == 1) ? Wk : (m == 2) ? Wv : Wp;
        int off = g0 & 65535;
#pragma unroll
        for (int e = 0; e < 8; ++e) {
            float2 f = *(const float2*)(src + off + e * 2);
            ((u32*)(Wb + g0))[e] = pk_bf16(f.x, f.y);
        }
    } else {
        // zero out[524288] fp32: 128 blocks x 256 thr x 16 floats
        size_t g0 = ((size_t)(bid - 448) * 256 + t) * 16;
        float4 z = {0.f, 0.f, 0.f, 0.f};
#pragma unroll
        for (int e = 0; e < 4; ++e)
            *(float4*)(out + g0 + e * 4) = z;
    }
}

// ---------------------------------------------------------------------------
// K1: QKV.  grid 2304 = 3 matrices x B x (L/32) x 4 np-chunks, 1 wave.
// Q/K: swapped-operand mfma(W, x) => b64 fragment stores.  V: original.
// Q pre-scaled by SCALE*LOG2E.
// ---------------------------------------------------------------------------
__global__ __launch_bounds__(64) void k_qkv(
    const u16* __restrict__ x, const u16* __restrict__ Wb,
    const float* __restrict__ bq, const float* __restrict__ bk,
    const float* __restrict__ bv,
    u16* __restrict__ Qf, u16* __restrict__ Kf, u16* __restrict__ Vf) {
    int bid = blockIdx.x;
    int npc = bid & 3;
    int rest = bid >> 2;
    int m  = rest / 192;         // 0=q 1=k 2=v
    int rb = rest % 192;
    int b  = rb / 96;
    int r0 = (rb % 96) * 32;
    int lane = threadIdx.x;
    int quad = lane >> 4, m16 = lane & 15;

    const u16* xrow0 = x + ((size_t)(b * L_ + r0 + m16)) * C_ + quad * 8;
    const u16* xrow1 = xrow0 + (size_t)16 * C_;
    short8 a0[8], a1[8];
#pragma unroll
    for (int kc = 0; kc < 8; ++kc) {
        a0[kc] = *(const short8*)(xrow0 + kc * 32);
        a1[kc] = *(const short8*)(xrow1 + kc * 32);
    }
    const u16* W = Wb + (size_t)m * 65536;

    if (m == 2) {
#pragma unroll
        for (int np = npc * 2; np < npc * 2 + 2; ++np) {
            int nt0 = np * 2;
            const u16* w0 = W + (size_t)(nt0 * 16 + m16) * C_ + quad * 8;
            const u16* w1 = w0 + 16 * C_;
            short8 wf0[8], wf1[8];
#pragma unroll
            for (int kc = 0; kc < 8; ++kc) {
                wf0[kc] = *(const short8*)(w0 + kc * 32);
                wf1[kc] = *(const short8*)(w1 + kc * 32);
            }
            floatx4 acc00 = {0.f,0.f,0.f,0.f}, acc01 = {0.f,0.f,0.f,0.f};
            floatx4 acc10 = {0.f,0.f,0.f,0.f}, acc11 = {0.f,0.f,0.f,0.f};
#pragma unroll
            for (int kc = 0; kc < 8; ++kc) {
                acc00 = __builtin_amdgcn_mfma_f32_16x16x32_bf16(a0[kc], wf0[kc], acc00, 0, 0, 0);
                acc01 = __builtin_amdgcn_mfma_f32_16x16x32_bf16(a0[kc], wf1[kc], acc01, 0, 0, 0);
                acc10 = __builtin_amdgcn_mfma_f32_16x16x32_bf16(a1[kc], wf0[kc], acc10, 0, 0, 0);
                acc11 = __builtin_amdgcn_mfma_f32_16x16x32_bf16(a1[kc], wf1[kc], acc11, 0, 0, 0);
            }
#pragma unroll
            for (int gi = 0; gi < 2; ++gi)
#pragma unroll
            for (int half = 0; half < 2; ++half) {
                int dout = (nt0 + half) * 16 + m16;
                float bias = bv[dout];
                int h = dout >> 6, dh = dout & 63;
                size_t bh = (size_t)(b * NH + h);
                floatx4 acc = gi ? (half ? acc11 : acc10) : (half ? acc01 : acc00);
                float f0 = acc[0] + bias, f1 = acc[1] + bias;
                float f2 = acc[2] + bias, f3 = acc[3] + bias;
                int lr0 = r0 + gi * 16 + quad * 4;
                int tile = lr0 >> 6, kk = lr0 & 63;
                int halfv = kk >> 5, quadp = (kk >> 3) & 3, j0 = kk & 7;
                int ntv = dh >> 4, m16pp = dh & 15;
                u32* p = (u32*)(Vf + (bh * 48 + tile) * 4096 +
                                ((size_t)((ntv * 2 + halfv) * 64 + quadp * 16 + m16pp)) * 8 + j0);
                p[0] = pk_bf16(f0, f1);
                p[1] = pk_bf16(f2, f3);
            }
        }
    } else {
        const float* bs = (m == 0) ? bq : bk;
        float scale = (m == 0) ? (SCALE * LOG2E) : 1.0f;
#pragma unroll
        for (int np = npc * 2; np < npc * 2 + 2; ++np) {
            int nt0 = np * 2;
            const u16* w0 = W + (size_t)(nt0 * 16 + m16) * C_ + quad * 8;
            const u16* w1 = w0 + 16 * C_;
            short8 wf0[8], wf1[8];
#pragma unroll
            for (int kc = 0; kc < 8; ++kc) {
                wf0[kc] = *(const short8*)(w0 + kc * 32);
                wf1[kc] = *(const short8*)(w1 + kc * 32);
            }
            floatx4 acc00 = {0.f,0.f,0.f,0.f}, acc01 = {0.f,0.f,0.f,0.f};
            floatx4 acc10 = {0.f,0.f,0.f,0.f}, acc11 = {0.f,0.f,0.f,0.f};
#pragma unroll
            for (int kc = 0; kc < 8; ++kc) {
                acc00 = __builtin_amdgcn_mfma_f32_16x16x32_bf16(wf0[kc], a0[kc], acc00, 0, 0, 0);
                acc01 = __builtin_amdgcn_mfma_f32_16x16x32_bf16(wf0[kc], a1[kc], acc01, 0, 0, 0);
                acc10 = __builtin_amdgcn_mfma_f32_16x16x32_bf16(wf1[kc], a0[kc], acc10, 0, 0, 0);
                acc11 = __builtin_amdgcn_mfma_f32_16x16x32_bf16(wf1[kc], a1[kc], acc11, 0, 0, 0);
            }
#pragma unroll
            for (int tt = 0; tt < 2; ++tt)
#pragma unroll
            for (int gi = 0; gi < 2; ++gi) {
                int ntb = (nt0 + tt) * 16;
                int h = ntb >> 6;
                size_t bh = (size_t)(b * NH + h);
                int dh0 = (ntb & 63) + quad * 4;
                int cc = dh0 >> 5, qp = (dh0 >> 3) & 3, j0 = dh0 & 7;
                float4 b4 = *(const float4*)(bs + ntb + quad * 4);
                floatx4 acc = tt ? (gi ? acc11 : acc10) : (gi ? acc01 : acc00);
                float f0 = (acc[0] + b4.x) * scale, f1 = (acc[1] + b4.y) * scale;
                float f2 = (acc[2] + b4.z) * scale, f3 = (acc[3] + b4.w) * scale;
                uint2 pk;
                pk.x = pk_bf16(f0, f1);
                pk.y = pk_bf16(f2, f3);
                int token = r0 + gi * 16 + m16;
                if (m == 0) {
                    int grp = (r0 >> 4) + gi;
                    *(uint2*)(Qf + (bh * 192 + grp) * 1024 +
                              (size_t)(cc * 64 + qp * 16 + m16) * 8 + j0) = pk;
                } else {
                    int tile = token >> 6;
                    int ntk = ((r0 & 63) >> 4) + gi;
                    *(uint2*)(Kf + (bh * 48 + tile) * 4096 +
                              (size_t)((ntk * 2 + cc) * 64 + qp * 16 + m16) * 8 + j0) = pk;
                }
            }
        }
    }
}

// ---------------------------------------------------------------------------
// K2: flash attention, S^T formulation (R8 best-measured version).
// 48 q-rows/wave (3 groups), 4 split-K waves x 12 tiles, single PL buffer.
// grid = B*NH*(L/48) = 512 blocks.
// ---------------------------------------------------------------------------
__global__ __launch_bounds__(256, 2) void k_attn(
    const u16* __restrict__ Qf, const u16* __restrict__ Kf,
    const u16* __restrict__ Vf, u16* __restrict__ o) {
    __shared__ __align__(16) char smem[36864];   // PL (27648B) then o_red
    __shared__ float l_red[3][3][16];
    u16* PL = (u16*)smem;
    float* o_red = (float*)smem;
    int bid = blockIdx.x;
    int qt = bid & 63;
    int h  = (bid >> 6) & 3;
    int b  = bid >> 8;
    int lane = threadIdx.x & 63;
    int w    = threadIdx.x >> 6;
    int quad = lane >> 4, m16 = lane & 15;
    int q0 = qt * 48;
    size_t bh = (size_t)(b * NH + h);

    const u16* qbase = Qf + (bh * 192 + qt * 3) * 1024 + (size_t)lane * 8;
    const u16* kbase = Kf + bh * 48 * 4096 + (size_t)lane * 8;
    const u16* vbase = Vf + bh * 48 * 4096 + (size_t)lane * 8;

    short8 aq[3][2];
#pragma unroll
    for (int g = 0; g < 3; ++g) {
        aq[g][0] = *(const short8*)(qbase + g * 1024);
        aq[g][1] = *(const short8*)(qbase + g * 1024 + 512);
    }

    float l_s[3] = {0.f, 0.f, 0.f};
    floatx4 o_acc[3][4];
#pragma unroll
    for (int g = 0; g < 3; ++g)
#pragma unroll
        for (int nt = 0; nt < 4; ++nt) o_acc[g][nt] = (floatx4){0.f, 0.f, 0.f, 0.f};

    int kt0 = w * 12;
    short8 kb[8], vb[8];
#pragma unroll
    for (int f = 0; f < 8; ++f)
        kb[f] = *(const short8*)(kbase + (size_t)kt0 * 4096 + f * 512);

    for (int i = 0; i < 12; ++i) {
        size_t tbase = (size_t)(kt0 + i) * 4096;
#pragma unroll
        for (int f = 0; f < 8; ++f)
            vb[f] = *(const short8*)(vbase + tbase + f * 512);
#pragma unroll
        for (int g = 0; g < 3; ++g) {
            floatx4 sx[4];
#pragma unroll
            for (int nt = 0; nt < 4; ++nt) {
                floatx4 z = {0.f, 0.f, 0.f, 0.f};
                z = __builtin_amdgcn_mfma_f32_16x16x32_bf16(kb[nt * 2], aq[g][0], z, 0, 0, 0);
                sx[nt] = __builtin_amdgcn_mfma_f32_16x16x32_bf16(kb[nt * 2 + 1], aq[g][1], z, 0, 0, 0);
            }
            u16* plrow = PL + (((w * 3 + g) * 16) + m16) * 72;
            float lsum = 0.f;
#pragma unroll
            for (int nt = 0; nt < 4; ++nt) {
                float p0 = __builtin_amdgcn_exp2f(sx[nt][0]);
                float p1 = __builtin_amdgcn_exp2f(sx[nt][1]);
                float p2 = __builtin_amdgcn_exp2f(sx[nt][2]);
                float p3 = __builtin_amdgcn_exp2f(sx[nt][3]);
                lsum += (p0 + p1) + (p2 + p3);
                uint2 pk; pk.x = pk_bf16(p0, p1); pk.y = pk_bf16(p2, p3);
                *(uint2*)(plrow + nt * 16 + quad * 4) = pk;
            }
            l_s[g] += lsum;
            short8 bp0 = *(const short8*)(plrow + quad * 8);
            short8 bp1 = *(const short8*)(plrow + 32 + quad * 8);
#pragma unroll
            for (int nt = 0; nt < 4; ++nt) {
                o_acc[g][nt] = __builtin_amdgcn_mfma_f32_16x16x32_bf16(vb[nt * 2], bp0, o_acc[g][nt], 0, 0, 0);
                o_acc[g][nt] = __builtin_amdgcn_mfma_f32_16x16x32_bf16(vb[nt * 2 + 1], bp1, o_acc[g][nt], 0, 0, 0);
            }
        }
        if (i < 11) {
#pragma unroll
            for (int f = 0; f < 8; ++f)
                kb[f] = *(const short8*)(kbase + tbase + 4096 + f * 512);
        }
    }
    float l_row[3];
#pragma unroll
    for (int g = 0; g < 3; ++g) {
        float ps = l_s[g];
        ps += __shfl_xor(ps, 16);
        ps += __shfl_xor(ps, 32);
        l_row[g] = ps;
    }
    __syncthreads();
    if (w > 0) {
#pragma unroll
        for (int g = 0; g < 3; ++g) {
#pragma unroll
            for (int nt = 0; nt < 4; ++nt)
                *(floatx4*)&o_red[(((w - 1) * 3 + g) * 4 + nt) * 256 + lane * 4] = o_acc[g][nt];
            if (quad == 0) l_red[w - 1][g][m16] = l_row[g];
        }
    }
    __syncthreads();
    if (w == 0) {
#pragma unroll
        for (int g = 0; g < 3; ++g) {
            float lt = __builtin_amdgcn_rcpf(
                l_row[g] + l_red[0][g][m16] + l_red[1][g][m16] + l_red[2][g][m16]);
#pragma unroll
            for (int nt = 0; nt < 4; ++nt) {
                floatx4 tot = o_acc[g][nt];
#pragma unroll
                for (int w1 = 0; w1 < 3; ++w1)
                    tot += *(const floatx4*)&o_red[((w1 * 3 + g) * 4 + nt) * 256 + lane * 4];
                uint2 pk;
                pk.x = pk_bf16(tot[0] * lt, tot[1] * lt);
                pk.y = pk_bf16(tot[2] * lt, tot[3] * lt);
                *(uint2*)(o + ((size_t)(b * L_ + q0 + g * 16 + m16)) * C_ +
                          h * 64 + nt * 16 + quad * 4) = pk;
            }
        }
    }
}

// ---------------------------------------------------------------------------
// K3: per-view proj + LayerNorm, swapped operands; 3-view mean accumulated
// directly into fp32 out[b][c][n] via atomicAdd (out pre-zeroed in K0).
// grid = V*B*(N/16) = 384 blocks, 4 waves.
// ---------------------------------------------------------------------------
__global__ __launch_bounds__(256) void k_proj_ln(
    const u16* __restrict__ o, const u16* __restrict__ Wpb,
    const float* __restrict__ bp,
    const float* __restrict__ gamma, const float* __restrict__ beta,
    float* __restrict__ out) {
    __shared__ float sred[4][16];
    __shared__ float sred2[4][16];
    int bid = blockIdx.x;
    int n0 = (bid & 63) << 4;
    int b  = (bid >> 6) & 1;
    int v  = bid >> 7;
    int lane = threadIdx.x & 63;
    int w    = threadIdx.x >> 6;
    int quad = lane >> 4, m16 = lane & 15;

    const u16* orow = o + ((size_t)(b * L_ + v * N_ + n0 + m16)) * C_ + quad * 8;
    short8 a[8];
#pragma unroll
    for (int kc = 0; kc < 8; ++kc) a[kc] = *(const short8*)(orow + kc * 32);

    float pr[4][4];
#pragma unroll
    for (int j = 0; j < 4; ++j) {
        int nt = w * 4 + j;
        const u16* wrow = Wpb + (size_t)(nt * 16 + m16) * C_ + quad * 8;
        floatx4 acc = {0.f, 0.f, 0.f, 0.f};
#pragma unroll
        for (int kc = 0; kc < 8; ++kc) {
            short8 bfr = *(const short8*)(wrow + kc * 32);
            acc = __builtin_amdgcn_mfma_f32_16x16x32_bf16(bfr, a[kc], acc, 0, 0, 0);
        }
        float4 b4 = *(const float4*)(bp + nt * 16 + quad * 4);
        pr[j][0] = acc[0] + b4.x; pr[j][1] = acc[1] + b4.y;
        pr[j][2] = acc[2] + b4.z; pr[j][3] = acc[3] + b4.w;
    }
    float sm = 0.f;
#pragma unroll
    for (int j = 0; j < 4; ++j)
        sm += (pr[j][0] + pr[j][1]) + (pr[j][2] + pr[j][3]);
    sm += __shfl_xor(sm, 16);
    sm += __shfl_xor(sm, 32);
    if (quad == 0) sred[w][m16] = sm;
    __syncthreads();
    float mu = (sred[0][m16] + sred[1][m16] + sred[2][m16] + sred[3][m16]) * (1.0f / C_);
    float sq = 0.f;
#pragma unroll
    for (int j = 0; j < 4; ++j)
#pragma unroll
        for (int r = 0; r < 4; ++r) { float d = pr[j][r] - mu; sq += d * d; }
    sq += __shfl_xor(sq, 16);
    sq += __shfl_xor(sq, 32);
    if (quad == 0) sred2[w][m16] = sq;
    __syncthreads();
    float var = (sred2[0][m16] + sred2[1][m16] + sred2[2][m16] + sred2[3][m16]) * (1.0f / C_);
    float rs = __builtin_amdgcn_rsqf(var + 1e-5f);
    int n = n0 + m16;
#pragma unroll
    for (int j = 0; j < 4; ++j) {
        int c0 = (w * 4 + j) * 16 + quad * 4;
        float4 g4 = *(const float4*)(gamma + c0);
        float4 be4 = *(const float4*)(beta + c0);
        float* obase = out + ((size_t)(b * C_ + c0)) * N_ + n;
        atomicAdd(obase,          ((pr[j][0] - mu) * rs * g4.x + be4.x) * (1.0f / 3.0f));
        atomicAdd(obase + N_,     ((pr[j][1] - mu) * rs * g4.y + be4.y) * (1.0f / 3.0f));
        atomicAdd(obase + 2 * N_, ((pr[j][2] - mu) * rs * g4.z + be4.z) * (1.0f / 3.0f));
        atomicAdd(obase + 3 * N_, ((pr[j][3] - mu) * rs * g4.w + be4.w) * (1.0f / 3.0f));
    }
}

extern "C" void kernel_launch(void* const* d_in, const int* in_sizes, int n_in,
                              void* d_out, int out_size, void* d_ws, size_t ws_size,
                              hipStream_t stream) {
    (void)in_sizes; (void)n_in; (void)out_size; (void)ws_size;
    const float* feat  = (const float*)d_in[0];
    const float* Wq    = (const float*)d_in[1];
    const float* bq    = (const float*)d_in[2];
    const float* Wk    = (const float*)d_in[3];
    const float* bk    = (const float*)d_in[4];
    const float* Wv    = (const float*)d_in[5];
    const float* bv    = (const float*)d_in[6];
    const float* Wp    = (const float*)d_in[7];
    const float* bp    = (const float*)d_in[8];
    const float* gamma = (const float*)d_in[9];
    const float* beta  = (const float*)d_in[10];
    float* out = (float*)d_out;

    size_t SZ = (size_t)B_ * L_ * C_;   // 1,572,864 elements
    u16* x   = (u16*)d_ws;
    u16* Qf  = x + SZ;
    u16* Kf  = Qf + SZ;
    u16* Vf  = Kf + SZ;
    u16* o   = Vf + SZ;
    u16* Wb  = o + SZ;                  // [4][65536] bf16 weights

    k_prep_gather<<<dim3(576), dim3(256), 0, stream>>>(feat, Wq, Wk, Wv, Wp, x, Wb, out);
    k_qkv<<<dim3(2304), dim3(64), 0, stream>>>(x, Wb, bq, bk, bv, Qf, Kf, Vf);
    k_attn<<<dim3(512), dim3(256), 0, stream>>>(Qf, Kf, Vf, o);
    k_proj_ln<<<dim3(384), dim3(256), 0, stream>>>(o, Wb + 3 * 65536, bp, gamma, beta, out);
}